// Round 8
// baseline (12.888 us; speedup 1.0000x reference)
//
#include <hip/hip_runtime.h>
#include <math.h>

#define NMODES 32
#define INV2PI 0.15915494309189535f

typedef short bf16x8 __attribute__((ext_vector_type(8)));  // 8 bf16 (4 VGPRs)
typedef float f32x4  __attribute__((ext_vector_type(4)));  // MFMA C/D
typedef unsigned int u32x4 __attribute__((ext_vector_type(4)));

// sin/cos of (2*pi*rev): v_sin/v_cos take REVOLUTIONS; reduce to [0,1) first.
__device__ inline void sincos_rev(float rev, float& s, float& c) {
    float f = rev - floorf(rev);
    s = __builtin_amdgcn_sinf(f);
    c = __builtin_amdgcn_cosf(f);
}

// one-instruction pack: (bf16rne(x0) | bf16rne(x1) << 16)
__device__ inline unsigned cvt_pk_bf16(float x0, float x1) {
    unsigned d;
    asm("v_cvt_pk_bf16_f32 %0, %1, %2" : "=v"(d) : "v"(x0), "v"(x1));
    return d;
}

// One 256-thread block (4 waves) per h. Wave w owns A-slab a=w (rows i=r+16w)
// and computes only B column-block b=w; setup + B shared via LDS.
// K[h, 64*i + d] = sum_k G[i,k] Q[k,d],   (factor 2 folded into Ct)
//   G[i, m] = Re(2Ct[m] exp(dtA[m] 64i)), G[i, m+32] = -Im(...)
//   Q[m, d] = Re(exp(dtA[m] d)),          Q[m+32, d] =  Im(...)
// MFMA operands SWAPPED -> D = (G Q)^T:
//   mfma(Qfrag, Gfrag): D[4g+reg][r] -> K[h][64*(16w+r) + 16b + 4g + reg]
// so each lane's 4 acc regs are 4 consecutive l -> one dwordx4 store per b.
__global__ __launch_bounds__(256, 4) void ssm_mfma_kernel(
    const float* __restrict__ C_real,      // (H, 32, 2)
    const float* __restrict__ log_dt,      // (H,)
    const float* __restrict__ log_A_real,  // (H, 32)
    const float* __restrict__ A_imag,      // (H, 32)
    float* __restrict__ K,                 // (H, L)
    int L)
{
    // per-mode params: [m] = {dAr, rhi, rlo, 2*Ctr, 2*Cti, -, -, -}
    __shared__ __align__(16) float sP[NMODES][8];
    __shared__ bf16x8 sB[16][64];          // [b*4+q][lane], 16 KiB

    const int h    = blockIdx.x;
    const int tid  = threadIdx.x;
    const int w    = tid >> 6;             // wave = a-slab = b-block owner
    const int lane = tid & 63;
    const int r    = lane & 15;
    const int g    = lane >> 4;            // lane's 8 modes: g*8 .. g*8+7

    // ---- Phase 1: per-mode setup; every thread computes mode tid&31
    // (8x redundant, uniform); lanes of wave 0 write.
    {
        const int m   = tid & 31;
        const int idx = h * NMODES + m;
        const float dt = __expf(log_dt[h]);
        const float Ar = -__expf(log_A_real[idx]);
        const float Ai = A_imag[idx];
        const float dAr = dt * Ar;
        const float dAi_rev = dt * Ai * INV2PI;     // phase step in revolutions

        // exact 12-bit split of the phase step
        const float rhi = __uint_as_float(__float_as_uint(dAi_rev) & 0xFFFFF000u);
        const float rlo = dAi_rev - rhi;            // exact (Sterbenz)

        // 2*Ct = 2 * C * (exp(dtA)-1) / A
        float sn, cs;
        sincos_rev(dAi_rev, sn, cs);
        const float er   = __expf(dAr);
        const float em1r = er * cs - 1.0f;
        const float em1i = er * sn;
        const float inv  = 2.0f * __builtin_amdgcn_rcpf(Ar * Ar + Ai * Ai);
        const float fr   = (em1r * Ar + em1i * Ai) * inv;
        const float fi   = (em1i * Ar - em1r * Ai) * inv;
        const float Cr   = C_real[idx * 2 + 0];
        const float Ci   = C_real[idx * 2 + 1];
        if (tid < 32) {
            sP[m][0] = dAr; sP[m][1] = rhi; sP[m][2] = rlo;
            sP[m][3] = Cr * fr - Ci * fi;
            sP[m][4] = Cr * fi + Ci * fr;
        }
    }
    __syncthreads();

    // ---- Phase 2: A frags (regs) + own B block (LDS). Params re-read from
    // LDS per pair -> no persistent register arrays (low liveness, no spill).
    u32x4 ah0, al0, ah1, al1;
    {
        const float t = (float)(64 * (r + 16 * w));  // <= 4032, 6 sig bits
#pragma unroll
        for (int jp = 0; jp < 4; ++jp) {
            const int m0 = g * 8 + 2 * jp;
            const float4 q0 = *(const float4*)&sP[m0][0];
            const float  c0 = sP[m0][4];
            const float4 q1 = *(const float4*)&sP[m0 + 1][0];
            const float  c1 = sP[m0 + 1][4];

            const float pm0 = __expf(q0.x * t);
            const float p0  = q0.y * t;                       // exact (12b x 6b)
            const float f0  = (p0 - floorf(p0)) + q0.z * t;   // rlo*t exact
            float zs0, zc0; sincos_rev(f0, zs0, zc0);
            const float gr0 = (q0.w * zc0 - c0 * zs0) * pm0;
            const float gi0 = (q0.w * zs0 + c0 * zc0) * -pm0; // -Im

            const float pm1 = __expf(q1.x * t);
            const float p1  = q1.y * t;
            const float f1  = (p1 - floorf(p1)) + q1.z * t;
            float zs1, zc1; sincos_rev(f1, zs1, zc1);
            const float gr1 = (q1.w * zc1 - c1 * zs1) * pm1;
            const float gi1 = (q1.w * zs1 + c1 * zc1) * -pm1;

            const unsigned hr = cvt_pk_bf16(gr0, gr1);
            const unsigned hi = cvt_pk_bf16(gi0, gi1);
            const float hr0 = __uint_as_float(hr << 16);
            const float hr1 = __uint_as_float(hr & 0xFFFF0000u);
            const float hi0 = __uint_as_float(hi << 16);
            const float hi1 = __uint_as_float(hi & 0xFFFF0000u);
            ah0[jp] = hr;
            ah1[jp] = hi;
            al0[jp] = cvt_pk_bf16(gr0 - hr0, gr1 - hr1);      // exact residuals
            al1[jp] = cvt_pk_bf16(gi0 - hi0, gi1 - hi1);
        }
    }
    const bf16x8 Ah0 = __builtin_bit_cast(bf16x8, ah0);
    const bf16x8 Al0 = __builtin_bit_cast(bf16x8, al0);
    const bf16x8 Ah1 = __builtin_bit_cast(bf16x8, ah1);
    const bf16x8 Al1 = __builtin_bit_cast(bf16x8, al1);

    {
        u32x4 bh0, bl0, bh1, bl1;
        const float d = (float)(r + 16 * w);         // < 64: rhi*d exact
#pragma unroll
        for (int jp = 0; jp < 4; ++jp) {
            const int m0 = g * 8 + 2 * jp;
            const float4 q0 = *(const float4*)&sP[m0][0];
            const float4 q1 = *(const float4*)&sP[m0 + 1][0];

            const float pm0 = __expf(q0.x * d);
            const float p0  = q0.y * d;
            const float f0  = (p0 - floorf(p0)) + q0.z * d;
            float qs0, qc0; sincos_rev(f0, qs0, qc0);
            const float qr0 = pm0 * qc0;
            const float qi0 = pm0 * qs0;

            const float pm1 = __expf(q1.x * d);
            const float p1  = q1.y * d;
            const float f1  = (p1 - floorf(p1)) + q1.z * d;
            float qs1, qc1; sincos_rev(f1, qs1, qc1);
            const float qr1 = pm1 * qc1;
            const float qi1 = pm1 * qs1;

            const unsigned hr = cvt_pk_bf16(qr0, qr1);
            const unsigned hi = cvt_pk_bf16(qi0, qi1);
            const float hr0 = __uint_as_float(hr << 16);
            const float hr1 = __uint_as_float(hr & 0xFFFF0000u);
            const float hi0 = __uint_as_float(hi << 16);
            const float hi1 = __uint_as_float(hi & 0xFFFF0000u);
            bh0[jp] = hr;
            bh1[jp] = hi;
            bl0[jp] = cvt_pk_bf16(qr0 - hr0, qr1 - hr1);
            bl1[jp] = cvt_pk_bf16(qi0 - hi0, qi1 - hi1);
        }
        sB[w * 4 + 0][lane] = __builtin_bit_cast(bf16x8, bh0);
        sB[w * 4 + 1][lane] = __builtin_bit_cast(bf16x8, bl0);
        sB[w * 4 + 2][lane] = __builtin_bit_cast(bf16x8, bh1);
        sB[w * 4 + 3][lane] = __builtin_bit_cast(bf16x8, bl1);
    }
    __syncthreads();

    // ---- Phase 3: 4 b-blocks x 6 MFMA, dwordx4 stores
    float* __restrict__ base = K + (size_t)h * L + 64 * (16 * w + r) + 4 * g;

#pragma unroll
    for (int b = 0; b < 4; ++b) {
        const bf16x8 Qh0 = sB[b * 4 + 0][lane];
        const bf16x8 Ql0 = sB[b * 4 + 1][lane];
        const bf16x8 Qh1 = sB[b * 4 + 2][lane];
        const bf16x8 Ql1 = sB[b * 4 + 3][lane];
        f32x4 acc = {0.f, 0.f, 0.f, 0.f};
        // hi*hi + lo*hi + hi*lo (lo*lo dropped, ~2^-18)
        acc = __builtin_amdgcn_mfma_f32_16x16x32_bf16(Qh0, Ah0, acc, 0, 0, 0);
        acc = __builtin_amdgcn_mfma_f32_16x16x32_bf16(Qh1, Ah1, acc, 0, 0, 0);
        acc = __builtin_amdgcn_mfma_f32_16x16x32_bf16(Ql0, Ah0, acc, 0, 0, 0);
        acc = __builtin_amdgcn_mfma_f32_16x16x32_bf16(Ql1, Ah1, acc, 0, 0, 0);
        acc = __builtin_amdgcn_mfma_f32_16x16x32_bf16(Qh0, Al0, acc, 0, 0, 0);
        acc = __builtin_amdgcn_mfma_f32_16x16x32_bf16(Qh1, Al1, acc, 0, 0, 0);
        *(f32x4*)(base + 16 * b) = acc;   // 16B-aligned: offset 16g + 64b bytes
    }
}

extern "C" void kernel_launch(void* const* d_in, const int* in_sizes, int n_in,
                              void* d_out, int out_size, void* d_ws, size_t ws_size,
                              hipStream_t stream) {
    const float* C_real     = (const float*)d_in[0];
    const float* log_dt     = (const float*)d_in[1];
    const float* log_A_real = (const float*)d_in[2];
    const float* A_imag     = (const float*)d_in[3];
    float* K = (float*)d_out;

    const int H = in_sizes[1];            // log_dt has H elements
    const int L = out_size / H;           // 4096

    ssm_mfma_kernel<<<H, 256, 0, stream>>>(
        C_real, log_dt, log_A_real, A_imag, K, L);
}